// Round 15
// baseline (194.660 us; speedup 1.0000x reference)
//
#include <hip/hip_runtime.h>
#include <stdint.h>

// YatCausalAttention on MI355X (gfx950).
// Inputs FP32, output FP32. Intermediates FP16 via f16 MFMA, fp32 accum.
// Pipeline: prep -> gemm<128> (BK=32, R21) -> yat flash attn (8-wave,
//           128-q blocks) -> gemm<64>.
// ws (fp16 elems): wqkvT 3072*1024 | woT 1024*1024 | qkv 4096*3072 | xh/attn 4096*1024 = 40 MB
// R25: attn scaled to 8 waves/block (512 thr), QBLK=128 — each wave owns its
// OWN 16 q-rows (per-wave VGPR unchanged ~56; R14/R15 failed by doubling
// per-wave state). Staging (K/V loads, sumsq, repack, ds_writes) is
// per-block-per-tile -> amortized over 8 waves not 4 (-~17% per-wave work).
// Grid (32,16)=512 blocks=2/CU; complementary yp map (15-y / y-8) pairs NT
// sums to 34 -> resident waves ~11-12/CU vs 9.3. LDS unchanged 37.9KB
// (Q stages into Kp[1]+Vt[1]). Causal: global row/col compare on last two
// tiles (low waves' final tile fully masked -> exp=0, alpha=1, exact).
// GEMMs = R21 BK=32 (R23/R24 BK=64 neutral-to-worse). prep unchanged.

#define TSEQ 2048
#define BATCH 2

typedef _Float16 f16x8 __attribute__((ext_vector_type(8)));
typedef _Float16 f16x2h __attribute__((ext_vector_type(2)));
typedef __fp16 fp16x2 __attribute__((ext_vector_type(2)));
typedef float f32x4 __attribute__((ext_vector_type(4)));
typedef unsigned int u32x2 __attribute__((ext_vector_type(2)));

#define MFMA16(a, b, c) __builtin_amdgcn_mfma_f32_16x16x32_f16(a, b, c, 0, 0, 0)

__device__ __forceinline__ unsigned short f2h(float f) {
  union { _Float16 h; unsigned short u; } v;
  v.h = (_Float16)f;
  return v.u;
}
__device__ __forceinline__ unsigned int pack2h(float lo, float hi) {
  return (unsigned int)f2h(lo) | ((unsigned int)f2h(hi) << 16);
}
// f32 acc += lo^2 + hi^2 of a packed f16 pair — single v_dot2_f32_f16
__device__ __forceinline__ float dot2acc(unsigned int u, float acc) {
  union { unsigned int u; f16x2h h; } c;
  c.u = u;
  return __builtin_amdgcn_fdot2(c.h, c.h, acc, false);
}
__device__ __forceinline__ void async_ld16(const void* g, const void* l) {
  __builtin_amdgcn_global_load_lds((const __attribute__((address_space(1))) void*)g,
                                   (__attribute__((address_space(3))) void*)l,
                                   16, 0, 0);
}
// pack two f32 -> one u32 of two f16 (v_cvt_pkrtz_f16_f32, single VALU op)
__device__ __forceinline__ unsigned int pk_f16(float lo, float hi) {
  union { fp16x2 h; unsigned int u; } c;
  c.h = __builtin_amdgcn_cvt_pkrtz(lo, hi);
  return c.u;
}

// ---------------- merged prep: cvt_x | transpose(w_qkv) | transpose(w_out) ----------------
__global__ __launch_bounds__(256) void prep(const float* __restrict__ x,
                                            unsigned short* __restrict__ xh,
                                            const float* __restrict__ w_qkv,
                                            unsigned short* __restrict__ wqkvT,
                                            const float* __restrict__ w_out,
                                            unsigned short* __restrict__ woT) {
  __shared__ unsigned short tile[32][33];
  const int bid = blockIdx.x, tid = threadIdx.x;
  if (bid < 2048) {
    const int i = (bid * 256 + tid) * 8;
    const float4 a = *(const float4*)(x + i);
    const float4 b = *(const float4*)(x + i + 4);
    uint4 o;
    o.x = pack2h(a.x, a.y); o.y = pack2h(a.z, a.w);
    o.z = pack2h(b.x, b.y); o.w = pack2h(b.z, b.w);
    *(uint4*)(xh + i) = o;
    return;
  }
  const bool qkv = bid < 5120;
  const int b2 = qkv ? bid - 2048 : bid - 5120;
  const int NB = qkv ? 96 : 32;            // N/32
  const int N = NB * 32, K = 1024;
  const float* src = qkv ? w_qkv : w_out;
  unsigned short* dst = qkv ? wqkvT : woT;
  const int nb = (b2 % NB) * 32, kb = (b2 / NB) * 32;
  const int tx = tid & 31, ty = tid >> 5;  // (32,8)
#pragma unroll
  for (int i = 0; i < 4; i++)
    tile[ty + 8 * i][tx] = f2h(src[(size_t)(kb + ty + 8 * i) * N + nb + tx]);
  __syncthreads();
#pragma unroll
  for (int i = 0; i < 4; i++)
    dst[(size_t)(nb + ty + 8 * i) * K + kb + tx] = tile[tx][ty + 8 * i];
}

// ------------- C[M][TN-tile] = A[M][K] * Bt[N][K]^T + bias[N]  (fp16 in, fp32 acc) -------------
// R21 GEMM: 128xTN tile, BK=32, global_load_lds width=16.
template <int TN, bool OUT_F32>
__global__ __launch_bounds__(256) void gemm_bt(const unsigned short* __restrict__ A,
                                               const unsigned short* __restrict__ Bt,
                                               const float* __restrict__ bias,
                                               void* __restrict__ Cp,
                                               int N, int K) {
  __shared__ __attribute__((aligned(16))) unsigned short Atile[128 * 32];
  __shared__ __attribute__((aligned(16))) unsigned short Btile[TN * 32];
  constexpr int NJ = TN / 32;  // 16-col tiles per wave
  const int tid = threadIdx.x;
  const int w = tid >> 6, lane = tid & 63;
  const int quad = lane >> 4, l15 = lane & 15;
  const int m0 = blockIdx.y * 128, n0 = blockIdx.x * TN;
  const int wr = w >> 1, wc = w & 1;
  const int nwc = wc * (TN / 2);
  f32x4 acc[4][NJ] = {};
  for (int kt = 0; kt < K; kt += 32) {
    __syncthreads();  // previous iteration's fragment reads complete
#pragma unroll
    for (int it = 0; it < 2; it++) {      // A: 128 rows
      const int c = it * 256 + tid;       // chunk: row = c>>2, 8-elem k-chunk = c&3
      async_ld16(A + (size_t)(m0 + (c >> 2)) * K + kt + (c & 3) * 8,
                 &Atile[(size_t)(it * 256 + w * 64) * 8]);   // wave-uniform LDS base
    }
#pragma unroll
    for (int it = 0; it < TN / 64; it++) {  // B: TN rows
      const int c = it * 256 + tid;
      async_ld16(Bt + (size_t)(n0 + (c >> 2)) * K + kt + (c & 3) * 8,
                 &Btile[(size_t)(it * 256 + w * 64) * 8]);
    }
    __syncthreads();  // vmcnt(0) drain lands the async copies
    f16x8 af[4], bfr[NJ];
#pragma unroll
    for (int i = 0; i < 4; i++)
      af[i] = *(const f16x8*)&Atile[(wr * 64 + i * 16 + l15) * 32 + quad * 8];
#pragma unroll
    for (int j = 0; j < NJ; j++)
      bfr[j] = *(const f16x8*)&Btile[(nwc + j * 16 + l15) * 32 + quad * 8];
#pragma unroll
    for (int i = 0; i < 4; i++)
#pragma unroll
      for (int j = 0; j < NJ; j++)
        acc[i][j] = MFMA16(af[i], bfr[j], acc[i][j]);
  }
  // epilogue: C/D layout col=lane&15, row=quad*4+reg
#pragma unroll
  for (int j = 0; j < NJ; j++) {
    const int n = n0 + nwc + j * 16 + l15;
    const float bv = bias[n];
#pragma unroll
    for (int i = 0; i < 4; i++) {
      const int mb = m0 + wr * 64 + i * 16 + quad * 4;
#pragma unroll
      for (int r = 0; r < 4; r++) {
        if constexpr (OUT_F32)
          ((float*)Cp)[(size_t)(mb + r) * N + n] = acc[i][j][r] + bv;
        else
          ((unsigned short*)Cp)[(size_t)(mb + r) * N + n] = f2h(acc[i][j][r] + bv);
      }
    }
  }
}

// ---------------- Yat causal flash attention (fp16 in/out, fp32 math) ----------------
// grid: (B*H, 16). Block 512 = 8 waves; wave w owns q rows [16w,16w+16) of a
// 128-row q block (rows 0-63 of Q staged in Kp[1], 64-127 in Vt[1]).
// score = dot^2 * rcp(qsq + ksq - 2 dot + 1e-6), causal, online softmax.
// S^T: accS = MFMA(K,Q) -> lane owns q = 16w+l15, t = nt*16+quad*4+r.
// Staging split over 8 waves (half the per-wave cost of the 4-wave version).
__global__ __launch_bounds__(512) void yat_attn(const unsigned short* __restrict__ qkv,
                                                unsigned short* __restrict__ outp) {
  __shared__ __attribute__((aligned(16))) unsigned short Kp[2][64 * 72];  // [t][d]; Kp[1]=Qlo
  __shared__ __attribute__((aligned(16))) unsigned short Vt[2][64 * 72];  // [d][t]; Vt[1]=Qhi
  __shared__ float qsq[128], ksq[2][64];
  const int tid = threadIdx.x;
  const int w = tid >> 6, lane = tid & 63;          // w = 0..7
  const int quad = lane >> 4, l15 = lane & 15;
  const int bh = blockIdx.x, b = bh >> 4, h = bh & 15;
  // complementary pair map: round1 (y<8) long blocks, round2 short; the two
  // blocks co-resident on a CU sum to NT_a + NT_b = 34.
  const int y = blockIdx.y;
  const int yp = (y < 8) ? 15 - y : y - 8;
  const int NT = 2 * yp + 2;   // k-tiles for this q block
  const int q0 = yp * 128;     // first q row
  const unsigned short* base = qkv + (size_t)b * TSEQ * 3072 + h * 64;
  const int t = tid >> 2, dcq = (tid & 3) * 16;  // Q staging: row t (0..127), 16 d's
  const int tk = tid >> 3, dk = (tid & 7) * 8;   // K staging: row tk (0..63), 8 d's
  const int d0 = tid & 31, tg = tid >> 5;        // V staging: d-pair d0, 4 t's (tg 0..15)

  // tile-0 K/V loads issued first (latency hides under Q staging)
  uint4 kreg;
  unsigned int vreg[4];
  {
    const unsigned short* gk = base + 1024 + (size_t)tk * 3072 + dk;
    kreg = *(const uint4*)gk;
    const unsigned short* gv = base + 2048 + (size_t)(tg * 4) * 3072 + 2 * d0;
#pragma unroll
    for (int s = 0; s < 4; s++)
      vreg[s] = *(const unsigned int*)(gv + (size_t)s * 3072);
  }
  {  // stage Q rows 0-63 -> Kp[1], 64-127 -> Vt[1]; qsq via v_dot2_f32_f16
    const unsigned short* g = base + (size_t)(q0 + t) * 3072 + dcq;
    uint4 v0 = *(const uint4*)g;
    uint4 v1 = *(const uint4*)(g + 8);
    unsigned short* qd = (t < 64) ? &Kp[1][t * 72 + dcq] : &Vt[1][(t - 64) * 72 + dcq];
    *(uint4*)qd = v0;
    *(uint4*)(qd + 8) = v1;
    float s = dot2acc(v0.x, 0.f);
    s = dot2acc(v0.y, s); s = dot2acc(v0.z, s); s = dot2acc(v0.w, s);
    s = dot2acc(v1.x, s); s = dot2acc(v1.y, s); s = dot2acc(v1.z, s);
    s = dot2acc(v1.w, s);
    s += __shfl_xor(s, 1);
    s += __shfl_xor(s, 2);
    if ((tid & 3) == 0) qsq[t] = s;
  }
  // commit K [t][d] + ksq + V^T [d][t] from regs into buffer `buf`
  auto commit = [&](int buf) {
    *(uint4*)&Kp[buf][tk * 72 + dk] = kreg;
    float s = dot2acc(kreg.x, 0.f);
    s = dot2acc(kreg.y, s); s = dot2acc(kreg.z, s); s = dot2acc(kreg.w, s);
    s += __shfl_xor(s, 1);
    s += __shfl_xor(s, 2);
    s += __shfl_xor(s, 4);
    if ((tid & 7) == 0) ksq[buf][tk] = s;
    // V^T repack: one v_perm_b32 per output dword (lo-halves / hi-halves)
    u32x2 LO, HI;
    LO.x = __builtin_amdgcn_perm(vreg[1], vreg[0], 0x05040100u);
    HI.x = __builtin_amdgcn_perm(vreg[1], vreg[0], 0x07060302u);
    LO.y = __builtin_amdgcn_perm(vreg[3], vreg[2], 0x05040100u);
    HI.y = __builtin_amdgcn_perm(vreg[3], vreg[2], 0x07060302u);
    *(u32x2*)&Vt[buf][(2 * d0) * 72 + tg * 4] = LO;
    *(u32x2*)&Vt[buf][(2 * d0 + 1) * 72 + tg * 4] = HI;
  };
  commit(0);
  {  // prefetch tile 1 (NT >= 2 always)
    const unsigned short* gk = base + 1024 + (size_t)(64 + tk) * 3072 + dk;
    kreg = *(const uint4*)gk;
    const unsigned short* gv = base + 2048 + (size_t)(64 + tg * 4) * 3072 + 2 * d0;
#pragma unroll
    for (int s = 0; s < 4; s++)
      vreg[s] = *(const unsigned int*)(gv + (size_t)s * 3072);
  }
  __syncthreads();  // Q (Kp[1]/Vt[1]) + tile0 (Kp[0]/Vt[0]/ksq[0]) visible
  // hoisted loop-invariant Q fragments (wave w: q rows 16w..16w+16)
  const unsigned short* qsrc =
      (w < 4) ? &Kp[1][(w * 16 + l15) * 72] : &Vt[1][((w - 4) * 16 + l15) * 72];
  const f16x8 aq0 = *(const f16x8*)(qsrc + quad * 8);
  const f16x8 aq1 = *(const f16x8*)(qsrc + 32 + quad * 8);
  const f16x8 onesf = {(_Float16)1.f, (_Float16)1.f, (_Float16)1.f, (_Float16)1.f,
                       (_Float16)1.f, (_Float16)1.f, (_Float16)1.f, (_Float16)1.f};
  const int qrow = w * 16 + l15;           // lane's q row within the 128-row block
  const float qsq_eps = qsq[qrow] + 1e-6f; // loop-invariant
  __syncthreads();  // all Q-frag reads done before kt=0 commits buf 1

  f32x4 accO[4] = {};                    // O^T: lane q = l15, d = 16i+quad*4+r
  float m_run = 0.f;                     // scores >= 0 so 0 is a valid init max
  float l_acc = 0.f;                     // l in O^T layout

  for (int kt = 0; kt < NT; kt++) {
    const int cur = kt & 1;
    // S^T = K Q^T : rows t (quad*4+r per nt), cols q (l15)
    f32x4 accS[4] = {};
#pragma unroll
    for (int nt = 0; nt < 4; nt++) {
      const f16x8 bk0 = *(const f16x8*)&Kp[cur][(nt * 16 + l15) * 72 + quad * 8];
      const f16x8 bk1 = *(const f16x8*)&Kp[cur][(nt * 16 + l15) * 72 + 32 + quad * 8];
      accS[nt] = MFMA16(bk0, aq0, accS[nt]);
      accS[nt] = MFMA16(bk1, aq1, accS[nt]);
    }
    // scores, packed-f32 vector form
    f32x4 sc[4];
#pragma unroll
    for (int nt = 0; nt < 4; nt++) {
      const f32x4 k4 = *(const f32x4*)&ksq[cur][nt * 16 + quad * 4];
      const f32x4 dv = accS[nt];
      f32x4 den = (k4 + qsq_eps) + dv * -2.f;  // v_pk_fma_f32
      f32x4 rc;
      rc[0] = __builtin_amdgcn_rcpf(den[0]);
      rc[1] = __builtin_amdgcn_rcpf(den[1]);
      rc[2] = __builtin_amdgcn_rcpf(den[2]);
      rc[3] = __builtin_amdgcn_rcpf(den[3]);
      sc[nt] = dv * dv * rc;                   // v_pk_mul_f32 x2
    }
    if (kt >= NT - 2) {  // causal region: last two tiles only
      const int koff = kt * 64 - q0 + 0;  // key_global - q0 base for tcol=0
#pragma unroll
      for (int nt = 0; nt < 4; nt++)
#pragma unroll
        for (int r = 0; r < 4; r++)
          if (koff + nt * 16 + quad * 4 + r > qrow) sc[nt][r] = -1e30f;
    }
    // row max: vector max tree, horizontal, cross-quad
    const f32x4 t01 = __builtin_elementwise_max(sc[0], sc[1]);
    const f32x4 t23 = __builtin_elementwise_max(sc[2], sc[3]);
    const f32x4 t4 = __builtin_elementwise_max(t01, t23);
    float tm = fmaxf(fmaxf(t4[0], t4[1]), fmaxf(t4[2], t4[3]));
    tm = fmaxf(tm, __shfl_xor(tm, 16));
    tm = fmaxf(tm, __shfl_xor(tm, 32));
    const float mn = fmaxf(m_run, tm);
    const float alpha = __expf(m_run - mn);
    m_run = mn;
    // P = exp(s - m) packed to f16 pairs
    unsigned int pa[4], pb[4];
#pragma unroll
    for (int nt = 0; nt < 4; nt++) {
      const f32x4 e = sc[nt] - m_run;
      pa[nt] = pk_f16(__expf(e[0]), __expf(e[1]));
      pb[nt] = pk_f16(__expf(e[2]), __expf(e[3]));
    }
    // commit tile kt+1 into the other buffer; issue loads for tile kt+2
    if (kt + 1 < NT) commit(cur ^ 1);
    if (kt + 2 < NT) {
      const unsigned short* gk = base + 1024 + (size_t)((kt + 2) * 64 + tk) * 3072 + dk;
      kreg = *(const uint4*)gk;
      const unsigned short* gv =
          base + 2048 + (size_t)((kt + 2) * 64 + tg * 4) * 3072 + 2 * d0;
#pragma unroll
      for (int s = 0; s < 4; s++)
        vreg[s] = *(const unsigned int*)(gv + (size_t)s * 3072);
    }
    // redistribute P into PV B-frags: (w0,w2) = permlane16(permlane32(lo,hi))
    union { f16x8 v; unsigned int u[4]; } bp0, bp1;
    {
      u32x2 s0 = __builtin_amdgcn_permlane32_swap(pa[0], pa[1], false, false);
      u32x2 s1 = __builtin_amdgcn_permlane16_swap(s0.x, s0.y, false, false);
      bp0.u[0] = s1.x; bp0.u[2] = s1.y;
      s0 = __builtin_amdgcn_permlane32_swap(pb[0], pb[1], false, false);
      s1 = __builtin_amdgcn_permlane16_swap(s0.x, s0.y, false, false);
      bp0.u[1] = s1.x; bp0.u[3] = s1.y;
      s0 = __builtin_amdgcn_permlane32_swap(pa[2], pa[3], false, false);
      s1 = __builtin_amdgcn_permlane16_swap(s0.x, s0.y, false, false);
      bp1.u[0] = s1.x; bp1.u[2] = s1.y;
      s0 = __builtin_amdgcn_permlane32_swap(pb[2], pb[3], false, false);
      s1 = __builtin_amdgcn_permlane16_swap(s0.x, s0.y, false, false);
      bp1.u[1] = s1.x; bp1.u[3] = s1.y;
    }
    // rescale O^T (v_pk_mul_f32), l via ones-MFMA, O^T += V^T P^T
#pragma unroll
    for (int i = 0; i < 4; i++) accO[i] *= alpha;
    f32x4 accL = {};
    accL = MFMA16(onesf, bp0.v, accL);
    accL = MFMA16(onesf, bp1.v, accL);
#pragma unroll
    for (int i = 0; i < 4; i++) {
      const f16x8 av0 = *(const f16x8*)&Vt[cur][(i * 16 + l15) * 72 + quad * 8];
      const f16x8 av1 = *(const f16x8*)&Vt[cur][(i * 16 + l15) * 72 + 32 + quad * 8];
      accO[i] = MFMA16(av0, bp0.v, accO[i]);
      accO[i] = MFMA16(av1, bp1.v, accO[i]);
    }
    l_acc = l_acc * alpha + accL[0];
    __syncthreads();  // reads of cur done; writes of cur^1 done
  }

  // finalize: divide by l, transpose through Kp[0] (rows 0-63) / Vt[0] (64-127)
  const float linv = 1.0f / l_acc;
  unsigned short* od =
      (w < 4) ? &Kp[0][(w * 16 + l15) * 72] : &Vt[0][((w - 4) * 16 + l15) * 72];
#pragma unroll
  for (int i = 0; i < 4; i++)
#pragma unroll
    for (int r = 0; r < 4; r++)
      od[i * 16 + quad * 4 + r] = f2h(accO[i][r] * linv);
  __syncthreads();
  {
    const unsigned short* os = (t < 64) ? &Kp[0][t * 72] : &Vt[0][(t - 64) * 72];
    uint4 o0 = *(const uint4*)(os + dcq);
    uint4 o1 = *(const uint4*)(os + dcq + 8);
    unsigned short* g = outp + (size_t)(b * TSEQ + q0 + t) * 1024 + h * 64 + dcq;
    *(uint4*)g = o0;
    *(uint4*)(g + 8) = o1;
  }
}

extern "C" void kernel_launch(void* const* d_in, const int* in_sizes, int n_in,
                              void* d_out, int out_size, void* d_ws, size_t ws_size,
                              hipStream_t stream) {
  (void)in_sizes; (void)n_in; (void)out_size; (void)ws_size;
  const float* x     = (const float*)d_in[0];  // [2,2048,1024] fp32
  const float* w_qkv = (const float*)d_in[1];  // [1024,3072]   fp32
  const float* b_qkv = (const float*)d_in[2];  // [3072]        fp32
  const float* w_out = (const float*)d_in[3];  // [1024,1024]   fp32
  const float* b_out = (const float*)d_in[4];  // [1024]        fp32
  float* out = (float*)d_out;                  // [2,2048,1024] fp32

  unsigned short* wqkvT  = (unsigned short*)d_ws;                    // [3072][1024] fp16
  unsigned short* woT    = wqkvT + (size_t)3072 * 1024;              // [1024][1024] fp16
  unsigned short* qkvws  = woT + (size_t)1024 * 1024;                // [4096][3072] fp16
  unsigned short* xh     = qkvws + (size_t)4096 * 3072;              // [4096][1024] fp16
  unsigned short* attnws = xh;  // alias: xh dead after gemm1, attnws born at yat_attn

  prep<<<dim3(6144), 256, 0, stream>>>(x, xh, w_qkv, wqkvT, w_out, woT);
  gemm_bt<128, false><<<dim3(3072 / 128, 4096 / 128), 256, 0, stream>>>(xh, wqkvT, b_qkv, qkvws, 3072, 1024);
  yat_attn<<<dim3(BATCH * 16, 16), 512, 0, stream>>>(qkvws, attnws);
  gemm_bt<64, true><<<dim3(1024 / 64, 4096 / 128), 256, 0, stream>>>(attnws, woT, b_out, out, 1024, 1024);
}

// Round 16
// 188.117 us; speedup vs baseline: 1.0348x; 1.0348x over previous
//
#include <hip/hip_runtime.h>
#include <stdint.h>

// YatCausalAttention on MI355X (gfx950).
// Inputs FP32, output FP32. Intermediates FP16 via f16 MFMA, fp32 accum.
// Pipeline: prep (cvt_x + weight transposes) -> gemm<128> -> yat flash attn
//           (64-q blocks) -> gemm<64>.
// ws (fp16 elems): wqkvT 3072*1024 | woT 1024*1024 | qkv 4096*3072 | xh/attn 4096*1024 = 40 MB
// R26 = R21 verbatim (best verified: 187.1us). Experiment ledger since:
// R22 cross-iter QK^T pipeline: neutral (wave-level overlap already covers);
// R23 BK=64: -12us (128B row stride -> all-lanes-one-bank-group, 9.4M confl);
// R24 BK=64+XOR swizzle: conflicts fixed but only break-even vs BK=32;
// R25 8-wave QBLK=128: neutral attn, worse total (coarser residency quanta).
// R21 config: attn QBLK=64 4-wave, dbuf K/V 1 barrier/iter, swapped QK^T,
// in-reg P (cvt_pkrtz+permlane), l via ones-MFMA, packed-f32 score math,
// dot2 sumsq, v_perm V-repack; GEMMs BK=32 global_load_lds; merged prep.

#define TSEQ 2048
#define BATCH 2

typedef _Float16 f16x8 __attribute__((ext_vector_type(8)));
typedef _Float16 f16x2h __attribute__((ext_vector_type(2)));
typedef __fp16 fp16x2 __attribute__((ext_vector_type(2)));
typedef float f32x4 __attribute__((ext_vector_type(4)));
typedef unsigned int u32x2 __attribute__((ext_vector_type(2)));

#define MFMA16(a, b, c) __builtin_amdgcn_mfma_f32_16x16x32_f16(a, b, c, 0, 0, 0)

__device__ __forceinline__ unsigned short f2h(float f) {
  union { _Float16 h; unsigned short u; } v;
  v.h = (_Float16)f;
  return v.u;
}
__device__ __forceinline__ unsigned int pack2h(float lo, float hi) {
  return (unsigned int)f2h(lo) | ((unsigned int)f2h(hi) << 16);
}
// f32 acc += lo^2 + hi^2 of a packed f16 pair — single v_dot2_f32_f16
__device__ __forceinline__ float dot2acc(unsigned int u, float acc) {
  union { unsigned int u; f16x2h h; } c;
  c.u = u;
  return __builtin_amdgcn_fdot2(c.h, c.h, acc, false);
}
__device__ __forceinline__ void async_ld16(const void* g, const void* l) {
  __builtin_amdgcn_global_load_lds((const __attribute__((address_space(1))) void*)g,
                                   (__attribute__((address_space(3))) void*)l,
                                   16, 0, 0);
}
// pack two f32 -> one u32 of two f16 (v_cvt_pkrtz_f16_f32, single VALU op)
__device__ __forceinline__ unsigned int pk_f16(float lo, float hi) {
  union { fp16x2 h; unsigned int u; } c;
  c.h = __builtin_amdgcn_cvt_pkrtz(lo, hi);
  return c.u;
}

// ---------------- merged prep: cvt_x | transpose(w_qkv) | transpose(w_out) ----------------
__global__ __launch_bounds__(256) void prep(const float* __restrict__ x,
                                            unsigned short* __restrict__ xh,
                                            const float* __restrict__ w_qkv,
                                            unsigned short* __restrict__ wqkvT,
                                            const float* __restrict__ w_out,
                                            unsigned short* __restrict__ woT) {
  __shared__ unsigned short tile[32][33];
  const int bid = blockIdx.x, tid = threadIdx.x;
  if (bid < 2048) {
    const int i = (bid * 256 + tid) * 8;
    const float4 a = *(const float4*)(x + i);
    const float4 b = *(const float4*)(x + i + 4);
    uint4 o;
    o.x = pack2h(a.x, a.y); o.y = pack2h(a.z, a.w);
    o.z = pack2h(b.x, b.y); o.w = pack2h(b.z, b.w);
    *(uint4*)(xh + i) = o;
    return;
  }
  const bool qkv = bid < 5120;
  const int b2 = qkv ? bid - 2048 : bid - 5120;
  const int NB = qkv ? 96 : 32;            // N/32
  const int N = NB * 32, K = 1024;
  const float* src = qkv ? w_qkv : w_out;
  unsigned short* dst = qkv ? wqkvT : woT;
  const int nb = (b2 % NB) * 32, kb = (b2 / NB) * 32;
  const int tx = tid & 31, ty = tid >> 5;  // (32,8)
#pragma unroll
  for (int i = 0; i < 4; i++)
    tile[ty + 8 * i][tx] = f2h(src[(size_t)(kb + ty + 8 * i) * N + nb + tx]);
  __syncthreads();
#pragma unroll
  for (int i = 0; i < 4; i++)
    dst[(size_t)(nb + ty + 8 * i) * K + kb + tx] = tile[tx][ty + 8 * i];
}

// ------------- C[M][TN-tile] = A[M][K] * Bt[N][K]^T + bias[N]  (fp16 in, fp32 acc) -------------
template <int TN, bool OUT_F32>
__global__ __launch_bounds__(256) void gemm_bt(const unsigned short* __restrict__ A,
                                               const unsigned short* __restrict__ Bt,
                                               const float* __restrict__ bias,
                                               void* __restrict__ Cp,
                                               int N, int K) {
  __shared__ __attribute__((aligned(16))) unsigned short Atile[128 * 32];
  __shared__ __attribute__((aligned(16))) unsigned short Btile[TN * 32];
  constexpr int NJ = TN / 32;  // 16-col tiles per wave
  const int tid = threadIdx.x;
  const int w = tid >> 6, lane = tid & 63;
  const int quad = lane >> 4, l15 = lane & 15;
  const int m0 = blockIdx.y * 128, n0 = blockIdx.x * TN;
  const int wr = w >> 1, wc = w & 1;
  const int nwc = wc * (TN / 2);
  f32x4 acc[4][NJ] = {};
  for (int kt = 0; kt < K; kt += 32) {
    __syncthreads();  // previous iteration's fragment reads complete
#pragma unroll
    for (int it = 0; it < 2; it++) {      // A: 128 rows
      const int c = it * 256 + tid;       // chunk: row = c>>2, 8-elem k-chunk = c&3
      async_ld16(A + (size_t)(m0 + (c >> 2)) * K + kt + (c & 3) * 8,
                 &Atile[(size_t)(it * 256 + w * 64) * 8]);   // wave-uniform LDS base
    }
#pragma unroll
    for (int it = 0; it < TN / 64; it++) {  // B: TN rows
      const int c = it * 256 + tid;
      async_ld16(Bt + (size_t)(n0 + (c >> 2)) * K + kt + (c & 3) * 8,
                 &Btile[(size_t)(it * 256 + w * 64) * 8]);
    }
    __syncthreads();  // vmcnt(0) drain lands the async copies
    f16x8 af[4], bfr[NJ];
#pragma unroll
    for (int i = 0; i < 4; i++)
      af[i] = *(const f16x8*)&Atile[(wr * 64 + i * 16 + l15) * 32 + quad * 8];
#pragma unroll
    for (int j = 0; j < NJ; j++)
      bfr[j] = *(const f16x8*)&Btile[(nwc + j * 16 + l15) * 32 + quad * 8];
#pragma unroll
    for (int i = 0; i < 4; i++)
#pragma unroll
      for (int j = 0; j < NJ; j++)
        acc[i][j] = MFMA16(af[i], bfr[j], acc[i][j]);
  }
  // epilogue: C/D layout col=lane&15, row=quad*4+reg
#pragma unroll
  for (int j = 0; j < NJ; j++) {
    const int n = n0 + nwc + j * 16 + l15;
    const float bv = bias[n];
#pragma unroll
    for (int i = 0; i < 4; i++) {
      const int mb = m0 + wr * 64 + i * 16 + quad * 4;
#pragma unroll
      for (int r = 0; r < 4; r++) {
        if constexpr (OUT_F32)
          ((float*)Cp)[(size_t)(mb + r) * N + n] = acc[i][j][r] + bv;
        else
          ((unsigned short*)Cp)[(size_t)(mb + r) * N + n] = f2h(acc[i][j][r] + bv);
      }
    }
  }
}

// ---------------- Yat causal flash attention (fp16 in/out, fp32 math) ----------------
// grid: (B*H, 32). Block 256 = 4 waves; wave w owns q rows [16w,16w+16).
// score = dot^2 * rcp(qsq + ksq - 2 dot + 1e-6), causal, online softmax.
// S^T layout: accS = MFMA(K,Q) -> lane owns q = w*16+l15, t = nt*16+quad*4+r.
// P in registers: cvt_pkrtz -> permlane32/16_swap -> PV B-frags.
// Double-buffered Kp/Vt/ksq: 1 barrier/iter. Kp[1] aliases Q staging.
__global__ __launch_bounds__(256, 4) void yat_attn(const unsigned short* __restrict__ qkv,
                                                   unsigned short* __restrict__ outp) {
  __shared__ __attribute__((aligned(16))) unsigned short Kp[2][64 * 72];  // [t][d]; Kp[1]=Q stage
  __shared__ __attribute__((aligned(16))) unsigned short Vt[2][64 * 72];  // [d][t]
  __shared__ float qsq[64], ksq[2][64];
  const int tid = threadIdx.x;
  const int w = tid >> 6, lane = tid & 63;
  const int quad = lane >> 4, l15 = lane & 15;
  const int bh = blockIdx.x, b = bh >> 4, h = bh & 15;
  // dispatch-round-aware qt map: per y-octave per CU; iteration sums uniform.
  const int y = blockIdx.y;
  const int qt = (y < 8) ? 31 - y : (y < 16) ? y - 8 : (y < 24) ? 39 - y : y - 16;
  const unsigned short* base = qkv + (size_t)b * TSEQ * 3072 + h * 64;
  const int t = tid >> 2, dc = (tid & 3) * 16;   // K/Q staging: row t, 16 d's
  const int d0 = tid & 31, tg8 = tid >> 5;       // V staging: 2 d-rows, 8 t's

  // tile-0 K/V loads issued first (latency hides under Q staging)
  uint4 kreg0, kreg1;
  unsigned int vreg[8];
  {
    const unsigned short* gk = base + 1024 + (size_t)t * 3072 + dc;
    kreg0 = *(const uint4*)gk;
    kreg1 = *(const uint4*)(gk + 8);
    const unsigned short* gv = base + 2048 + (size_t)(tg8 * 8) * 3072 + 2 * d0;
#pragma unroll
    for (int s = 0; s < 8; s++)
      vreg[s] = *(const unsigned int*)(gv + (size_t)s * 3072);
  }
  {  // stage Q tile into Kp[1] + row sums of squares (v_dot2_f32_f16)
    const unsigned short* g = base + (size_t)(qt * 64 + t) * 3072 + dc;
    uint4 v0 = *(const uint4*)g;
    uint4 v1 = *(const uint4*)(g + 8);
    *(uint4*)&Kp[1][t * 72 + dc] = v0;
    *(uint4*)&Kp[1][t * 72 + dc + 8] = v1;
    float s = dot2acc(v0.x, 0.f);
    s = dot2acc(v0.y, s); s = dot2acc(v0.z, s); s = dot2acc(v0.w, s);
    s = dot2acc(v1.x, s); s = dot2acc(v1.y, s); s = dot2acc(v1.z, s);
    s = dot2acc(v1.w, s);
    s += __shfl_xor(s, 1);
    s += __shfl_xor(s, 2);
    if ((tid & 3) == 0) qsq[t] = s;
  }
  // commit K [t][d] + ksq + V^T [d][t] from regs into buffer `buf`
  auto commit = [&](int buf) {
    *(uint4*)&Kp[buf][t * 72 + dc] = kreg0;
    *(uint4*)&Kp[buf][t * 72 + dc + 8] = kreg1;
    float s = dot2acc(kreg0.x, 0.f);
    s = dot2acc(kreg0.y, s); s = dot2acc(kreg0.z, s); s = dot2acc(kreg0.w, s);
    s = dot2acc(kreg1.x, s); s = dot2acc(kreg1.y, s); s = dot2acc(kreg1.z, s);
    s = dot2acc(kreg1.w, s);
    s += __shfl_xor(s, 1);
    s += __shfl_xor(s, 2);
    if ((tid & 3) == 0) ksq[buf][t] = s;
    // V^T repack: one v_perm_b32 per output dword (lo-halves / hi-halves)
    uint4 LO, HI;
    LO.x = __builtin_amdgcn_perm(vreg[1], vreg[0], 0x05040100u);
    HI.x = __builtin_amdgcn_perm(vreg[1], vreg[0], 0x07060302u);
    LO.y = __builtin_amdgcn_perm(vreg[3], vreg[2], 0x05040100u);
    HI.y = __builtin_amdgcn_perm(vreg[3], vreg[2], 0x07060302u);
    LO.z = __builtin_amdgcn_perm(vreg[5], vreg[4], 0x05040100u);
    HI.z = __builtin_amdgcn_perm(vreg[5], vreg[4], 0x07060302u);
    LO.w = __builtin_amdgcn_perm(vreg[7], vreg[6], 0x05040100u);
    HI.w = __builtin_amdgcn_perm(vreg[7], vreg[6], 0x07060302u);
    *(uint4*)&Vt[buf][(2 * d0) * 72 + tg8 * 8] = LO;
    *(uint4*)&Vt[buf][(2 * d0 + 1) * 72 + tg8 * 8] = HI;
  };
  commit(0);
  if (qt >= 1) {  // prefetch tile 1
    const unsigned short* gk = base + 1024 + (size_t)(64 + t) * 3072 + dc;
    kreg0 = *(const uint4*)gk;
    kreg1 = *(const uint4*)(gk + 8);
    const unsigned short* gv = base + 2048 + (size_t)(64 + tg8 * 8) * 3072 + 2 * d0;
#pragma unroll
    for (int s = 0; s < 8; s++)
      vreg[s] = *(const unsigned int*)(gv + (size_t)s * 3072);
  }
  __syncthreads();  // Q (Kp[1]) + tile0 (Kp[0]/Vt[0]/ksq[0]) visible
  // hoisted loop-invariant Q fragments (wave w, q rows 16w..16w+16)
  const f16x8 aq0 = *(const f16x8*)&Kp[1][(w * 16 + l15) * 72 + quad * 8];
  const f16x8 aq1 = *(const f16x8*)&Kp[1][(w * 16 + l15) * 72 + 32 + quad * 8];
  const f16x8 onesf = {(_Float16)1.f, (_Float16)1.f, (_Float16)1.f, (_Float16)1.f,
                       (_Float16)1.f, (_Float16)1.f, (_Float16)1.f, (_Float16)1.f};
  const int ql = w * 16 + l15;            // this lane's q row (tile-local)
  const float qsq_eps = qsq[ql] + 1e-6f;  // loop-invariant
  __syncthreads();  // all Q-frag reads done before iter0 commits into Kp[1]

  f32x4 accO[4] = {};                    // O^T: lane q = l15, d = 16i+quad*4+r
  float m_run = 0.f;                     // scores >= 0 so 0 is a valid init max
  float l_acc = 0.f;                     // l in O^T layout: lane q = l15

  for (int kt = 0; kt <= qt; kt++) {
    const int cur = kt & 1;
    // S^T = K Q^T : rows t (quad*4+r per nt), cols q (l15) — critical path first
    f32x4 accS[4] = {};
#pragma unroll
    for (int nt = 0; nt < 4; nt++) {
      const f16x8 bk0 = *(const f16x8*)&Kp[cur][(nt * 16 + l15) * 72 + quad * 8];
      const f16x8 bk1 = *(const f16x8*)&Kp[cur][(nt * 16 + l15) * 72 + 32 + quad * 8];
      accS[nt] = MFMA16(bk0, aq0, accS[nt]);
      accS[nt] = MFMA16(bk1, aq1, accS[nt]);
    }
    // scores, packed-f32 vector form: lane q = ql, t = nt*16 + quad*4 + r
    f32x4 sc[4];
#pragma unroll
    for (int nt = 0; nt < 4; nt++) {
      const f32x4 k4 = *(const f32x4*)&ksq[cur][nt * 16 + quad * 4];
      const f32x4 dv = accS[nt];
      f32x4 den = (k4 + qsq_eps) + dv * -2.f;  // contracts to v_pk_fma_f32
      f32x4 rc;
      rc[0] = __builtin_amdgcn_rcpf(den[0]);
      rc[1] = __builtin_amdgcn_rcpf(den[1]);
      rc[2] = __builtin_amdgcn_rcpf(den[2]);
      rc[3] = __builtin_amdgcn_rcpf(den[3]);
      sc[nt] = dv * dv * rc;                   // v_pk_mul_f32 x2
    }
    if (kt == qt) {  // causal mask, uniform branch (last iteration only)
#pragma unroll
      for (int nt = 0; nt < 4; nt++)
#pragma unroll
        for (int r = 0; r < 4; r++)
          if (nt * 16 + quad * 4 + r > ql) sc[nt][r] = -1e30f;
    }
    // row max: vector pk_max tree, then horizontal, then cross-quad
    const f32x4 t01 = __builtin_elementwise_max(sc[0], sc[1]);
    const f32x4 t23 = __builtin_elementwise_max(sc[2], sc[3]);
    const f32x4 t4 = __builtin_elementwise_max(t01, t23);
    float tm = fmaxf(fmaxf(t4[0], t4[1]), fmaxf(t4[2], t4[3]));
    tm = fmaxf(tm, __shfl_xor(tm, 16));
    tm = fmaxf(tm, __shfl_xor(tm, 32));
    const float mn = fmaxf(m_run, tm);
    const float alpha = __expf(m_run - mn);
    m_run = mn;
    // P = exp(s - m) packed to f16 pairs
    unsigned int pa[4], pb[4];
#pragma unroll
    for (int nt = 0; nt < 4; nt++) {
      const f32x4 e = sc[nt] - m_run;          // v_pk_add_f32 x2
      pa[nt] = pk_f16(__expf(e[0]), __expf(e[1]));
      pb[nt] = pk_f16(__expf(e[2]), __expf(e[3]));
    }
    // commit tile kt+1 into the other buffer (vmcnt wait lands here, ~1 iter
    // after load issue); then issue loads for tile kt+2.
    if (kt < qt) commit(cur ^ 1);
    if (kt + 2 <= qt) {
      const unsigned short* gk = base + 1024 + (size_t)((kt + 2) * 64 + t) * 3072 + dc;
      kreg0 = *(const uint4*)gk;
      kreg1 = *(const uint4*)(gk + 8);
      const unsigned short* gv =
          base + 2048 + (size_t)((kt + 2) * 64 + tg8 * 8) * 3072 + 2 * d0;
#pragma unroll
      for (int s = 0; s < 8; s++)
        vreg[s] = *(const unsigned int*)(gv + (size_t)s * 3072);
    }
    // redistribute P into PV B-frags: (w0,w2) = permlane16(permlane32(lo,hi))
    union { f16x8 v; unsigned int u[4]; } bp0, bp1;
    {
      u32x2 s0 = __builtin_amdgcn_permlane32_swap(pa[0], pa[1], false, false);
      u32x2 s1 = __builtin_amdgcn_permlane16_swap(s0.x, s0.y, false, false);
      bp0.u[0] = s1.x; bp0.u[2] = s1.y;
      s0 = __builtin_amdgcn_permlane32_swap(pb[0], pb[1], false, false);
      s1 = __builtin_amdgcn_permlane16_swap(s0.x, s0.y, false, false);
      bp0.u[1] = s1.x; bp0.u[3] = s1.y;
      s0 = __builtin_amdgcn_permlane32_swap(pa[2], pa[3], false, false);
      s1 = __builtin_amdgcn_permlane16_swap(s0.x, s0.y, false, false);
      bp1.u[0] = s1.x; bp1.u[2] = s1.y;
      s0 = __builtin_amdgcn_permlane32_swap(pb[2], pb[3], false, false);
      s1 = __builtin_amdgcn_permlane16_swap(s0.x, s0.y, false, false);
      bp1.u[1] = s1.x; bp1.u[3] = s1.y;
    }
    // rescale O^T (vector: v_pk_mul_f32 x2 each), l via ones-MFMA
#pragma unroll
    for (int i = 0; i < 4; i++) accO[i] *= alpha;
    f32x4 accL = {};  // D = ones * P^T -> col=l15=q, rows identical = sum_t P[q][t]
    accL = MFMA16(onesf, bp0.v, accL);
    accL = MFMA16(onesf, bp1.v, accL);
#pragma unroll
    for (int i = 0; i < 4; i++) {
      const f16x8 av0 = *(const f16x8*)&Vt[cur][(i * 16 + l15) * 72 + quad * 8];
      const f16x8 av1 = *(const f16x8*)&Vt[cur][(i * 16 + l15) * 72 + 32 + quad * 8];
      accO[i] = MFMA16(av0, bp0.v, accO[i]);
      accO[i] = MFMA16(av1, bp1.v, accO[i]);
    }
    l_acc = l_acc * alpha + accL[0];
    __syncthreads();  // single barrier: reads of cur done; writes of cur^1 done
  }

  // finalize: divide by l (already in O^T lane layout), transpose via Kp[0], store
  const float linv = 1.0f / l_acc;
#pragma unroll
  for (int i = 0; i < 4; i++)
#pragma unroll
    for (int r = 0; r < 4; r++)
      Kp[0][(w * 16 + l15) * 72 + i * 16 + quad * 4 + r] = f2h(accO[i][r] * linv);
  __syncthreads();
  {
    uint4 o0 = *(const uint4*)&Kp[0][t * 72 + dc];
    uint4 o1 = *(const uint4*)&Kp[0][t * 72 + dc + 8];
    unsigned short* g = outp + (size_t)(b * TSEQ + qt * 64 + t) * 1024 + h * 64 + dc;
    *(uint4*)g = o0;
    *(uint4*)(g + 8) = o1;
  }
}

extern "C" void kernel_launch(void* const* d_in, const int* in_sizes, int n_in,
                              void* d_out, int out_size, void* d_ws, size_t ws_size,
                              hipStream_t stream) {
  (void)in_sizes; (void)n_in; (void)out_size; (void)ws_size;
  const float* x     = (const float*)d_in[0];  // [2,2048,1024] fp32
  const float* w_qkv = (const float*)d_in[1];  // [1024,3072]   fp32
  const float* b_qkv = (const float*)d_in[2];  // [3072]        fp32
  const float* w_out = (const float*)d_in[3];  // [1024,1024]   fp32
  const float* b_out = (const float*)d_in[4];  // [1024]        fp32
  float* out = (float*)d_out;                  // [2,2048,1024] fp32

  unsigned short* wqkvT  = (unsigned short*)d_ws;                    // [3072][1024] fp16
  unsigned short* woT    = wqkvT + (size_t)3072 * 1024;              // [1024][1024] fp16
  unsigned short* qkvws  = woT + (size_t)1024 * 1024;                // [4096][3072] fp16
  unsigned short* xh     = qkvws + (size_t)4096 * 3072;              // [4096][1024] fp16
  unsigned short* attnws = xh;  // alias: xh dead after gemm1, attnws born at yat_attn

  prep<<<dim3(6144), 256, 0, stream>>>(x, xh, w_qkv, wqkvT, w_out, woT);
  gemm_bt<128, false><<<dim3(3072 / 128, 4096 / 128), 256, 0, stream>>>(xh, wqkvT, b_qkv, qkvws, 3072, 1024);
  yat_attn<<<dim3(BATCH * 16, 32), 256, 0, stream>>>(qkvws, attnws);
  gemm_bt<64, true><<<dim3(1024 / 64, 4096 / 128), 256, 0, stream>>>(attnws, woT, b_out, out, 1024, 1024);
}

// Round 17
// 187.318 us; speedup vs baseline: 1.0392x; 1.0043x over previous
//
#include <hip/hip_runtime.h>
#include <stdint.h>

// YatCausalAttention on MI355X (gfx950).
// Inputs FP32, output FP32. Intermediates FP16 via f16 MFMA, fp32 accum.
// Pipeline: prep (cvt_x + weight transposes) -> gemm<128> -> yat flash attn
//           (64-q blocks) -> gemm<64>.
// ws (fp16 elems): wqkvT 3072*1024 | woT 1024*1024 | qkv 4096*3072 | xh/attn 4096*1024 = 40 MB
// R27 = R26 + T1 XCD-chunked block swizzle on both GEMMs. R23's profile
// showed gemm1 FETCH 40MB vs compulsory 14MB: round-robin XCD dispatch makes
// consecutive blocks (which share A/B panels) land on different per-XCD L2s.
// Chunked remap logical=(bid%8)*(nwg/8)+bid/8 gives each XCD a contiguous
// 96-tile run (4 A-panel rows) -> panel re-reads become XCD-local L2 hits
// (catalog T1: +10% HBM-bound GEMM; nwg 768/512 both %8==0 -> bijective).
// Pure index remap, bit-identical output. attn untouched (FETCH==compulsory,
// nothing to recover; 6 structural attn attempts all null — see R22-R25).
// R26/R21 config otherwise: attn QBLK=64 4-wave dbuf, swapped QK^T, in-reg P
// (cvt_pkrtz+permlane), ones-MFMA l, packed-f32 scores; GEMM BK=32; prep.

#define TSEQ 2048
#define BATCH 2

typedef _Float16 f16x8 __attribute__((ext_vector_type(8)));
typedef _Float16 f16x2h __attribute__((ext_vector_type(2)));
typedef __fp16 fp16x2 __attribute__((ext_vector_type(2)));
typedef float f32x4 __attribute__((ext_vector_type(4)));
typedef unsigned int u32x2 __attribute__((ext_vector_type(2)));

#define MFMA16(a, b, c) __builtin_amdgcn_mfma_f32_16x16x32_f16(a, b, c, 0, 0, 0)

__device__ __forceinline__ unsigned short f2h(float f) {
  union { _Float16 h; unsigned short u; } v;
  v.h = (_Float16)f;
  return v.u;
}
__device__ __forceinline__ unsigned int pack2h(float lo, float hi) {
  return (unsigned int)f2h(lo) | ((unsigned int)f2h(hi) << 16);
}
// f32 acc += lo^2 + hi^2 of a packed f16 pair — single v_dot2_f32_f16
__device__ __forceinline__ float dot2acc(unsigned int u, float acc) {
  union { unsigned int u; f16x2h h; } c;
  c.u = u;
  return __builtin_amdgcn_fdot2(c.h, c.h, acc, false);
}
__device__ __forceinline__ void async_ld16(const void* g, const void* l) {
  __builtin_amdgcn_global_load_lds((const __attribute__((address_space(1))) void*)g,
                                   (__attribute__((address_space(3))) void*)l,
                                   16, 0, 0);
}
// pack two f32 -> one u32 of two f16 (v_cvt_pkrtz_f16_f32, single VALU op)
__device__ __forceinline__ unsigned int pk_f16(float lo, float hi) {
  union { fp16x2 h; unsigned int u; } c;
  c.h = __builtin_amdgcn_cvt_pkrtz(lo, hi);
  return c.u;
}

// ---------------- merged prep: cvt_x | transpose(w_qkv) | transpose(w_out) ----------------
__global__ __launch_bounds__(256) void prep(const float* __restrict__ x,
                                            unsigned short* __restrict__ xh,
                                            const float* __restrict__ w_qkv,
                                            unsigned short* __restrict__ wqkvT,
                                            const float* __restrict__ w_out,
                                            unsigned short* __restrict__ woT) {
  __shared__ unsigned short tile[32][33];
  const int bid = blockIdx.x, tid = threadIdx.x;
  if (bid < 2048) {
    const int i = (bid * 256 + tid) * 8;
    const float4 a = *(const float4*)(x + i);
    const float4 b = *(const float4*)(x + i + 4);
    uint4 o;
    o.x = pack2h(a.x, a.y); o.y = pack2h(a.z, a.w);
    o.z = pack2h(b.x, b.y); o.w = pack2h(b.z, b.w);
    *(uint4*)(xh + i) = o;
    return;
  }
  const bool qkv = bid < 5120;
  const int b2 = qkv ? bid - 2048 : bid - 5120;
  const int NB = qkv ? 96 : 32;            // N/32
  const int N = NB * 32, K = 1024;
  const float* src = qkv ? w_qkv : w_out;
  unsigned short* dst = qkv ? wqkvT : woT;
  const int nb = (b2 % NB) * 32, kb = (b2 / NB) * 32;
  const int tx = tid & 31, ty = tid >> 5;  // (32,8)
#pragma unroll
  for (int i = 0; i < 4; i++)
    tile[ty + 8 * i][tx] = f2h(src[(size_t)(kb + ty + 8 * i) * N + nb + tx]);
  __syncthreads();
#pragma unroll
  for (int i = 0; i < 4; i++)
    dst[(size_t)(nb + ty + 8 * i) * K + kb + tx] = tile[tx][ty + 8 * i];
}

// ------------- C[M][TN-tile] = A[M][K] * Bt[N][K]^T + bias[N]  (fp16 in, fp32 acc) -------------
// Launched on a 1-D grid of NWGX*NWGY blocks; T1 XCD-chunked swizzle maps the
// hardware block id to logical (x,y): logical = (bid%8)*(nwg/8) + bid/8 so
// each XCD owns a contiguous tile run (A-panels stay in its private L2).
template <int TN, bool OUT_F32, int NWGX>
__global__ __launch_bounds__(256) void gemm_bt(const unsigned short* __restrict__ A,
                                               const unsigned short* __restrict__ Bt,
                                               const float* __restrict__ bias,
                                               void* __restrict__ Cp,
                                               int N, int K, int nwg) {
  __shared__ __attribute__((aligned(16))) unsigned short Atile[128 * 32];
  __shared__ __attribute__((aligned(16))) unsigned short Btile[TN * 32];
  constexpr int NJ = TN / 32;  // 16-col tiles per wave
  const int tid = threadIdx.x;
  const int w = tid >> 6, lane = tid & 63;
  const int quad = lane >> 4, l15 = lane & 15;
  // XCD-chunked swizzle (nwg % 8 == 0 -> bijective)
  const int bid = blockIdx.x;
  const int logical = (bid & 7) * (nwg >> 3) + (bid >> 3);
  const int m0 = (logical / NWGX) * 128, n0 = (logical % NWGX) * TN;
  const int wr = w >> 1, wc = w & 1;
  const int nwc = wc * (TN / 2);
  f32x4 acc[4][NJ] = {};
  for (int kt = 0; kt < K; kt += 32) {
    __syncthreads();  // previous iteration's fragment reads complete
#pragma unroll
    for (int it = 0; it < 2; it++) {      // A: 128 rows
      const int c = it * 256 + tid;       // chunk: row = c>>2, 8-elem k-chunk = c&3
      async_ld16(A + (size_t)(m0 + (c >> 2)) * K + kt + (c & 3) * 8,
                 &Atile[(size_t)(it * 256 + w * 64) * 8]);   // wave-uniform LDS base
    }
#pragma unroll
    for (int it = 0; it < TN / 64; it++) {  // B: TN rows
      const int c = it * 256 + tid;
      async_ld16(Bt + (size_t)(n0 + (c >> 2)) * K + kt + (c & 3) * 8,
                 &Btile[(size_t)(it * 256 + w * 64) * 8]);
    }
    __syncthreads();  // vmcnt(0) drain lands the async copies
    f16x8 af[4], bfr[NJ];
#pragma unroll
    for (int i = 0; i < 4; i++)
      af[i] = *(const f16x8*)&Atile[(wr * 64 + i * 16 + l15) * 32 + quad * 8];
#pragma unroll
    for (int j = 0; j < NJ; j++)
      bfr[j] = *(const f16x8*)&Btile[(nwc + j * 16 + l15) * 32 + quad * 8];
#pragma unroll
    for (int i = 0; i < 4; i++)
#pragma unroll
      for (int j = 0; j < NJ; j++)
        acc[i][j] = MFMA16(af[i], bfr[j], acc[i][j]);
  }
  // epilogue: C/D layout col=lane&15, row=quad*4+reg
#pragma unroll
  for (int j = 0; j < NJ; j++) {
    const int n = n0 + nwc + j * 16 + l15;
    const float bv = bias[n];
#pragma unroll
    for (int i = 0; i < 4; i++) {
      const int mb = m0 + wr * 64 + i * 16 + quad * 4;
#pragma unroll
      for (int r = 0; r < 4; r++) {
        if constexpr (OUT_F32)
          ((float*)Cp)[(size_t)(mb + r) * N + n] = acc[i][j][r] + bv;
        else
          ((unsigned short*)Cp)[(size_t)(mb + r) * N + n] = f2h(acc[i][j][r] + bv);
      }
    }
  }
}

// ---------------- Yat causal flash attention (fp16 in/out, fp32 math) ----------------
// grid: (B*H, 32). Block 256 = 4 waves; wave w owns q rows [16w,16w+16).
// score = dot^2 * rcp(qsq + ksq - 2 dot + 1e-6), causal, online softmax.
// S^T layout: accS = MFMA(K,Q) -> lane owns q = w*16+l15, t = nt*16+quad*4+r.
// P in registers: cvt_pkrtz -> permlane32/16_swap -> PV B-frags.
// Double-buffered Kp/Vt/ksq: 1 barrier/iter. Kp[1] aliases Q staging.
__global__ __launch_bounds__(256, 4) void yat_attn(const unsigned short* __restrict__ qkv,
                                                   unsigned short* __restrict__ outp) {
  __shared__ __attribute__((aligned(16))) unsigned short Kp[2][64 * 72];  // [t][d]; Kp[1]=Q stage
  __shared__ __attribute__((aligned(16))) unsigned short Vt[2][64 * 72];  // [d][t]
  __shared__ float qsq[64], ksq[2][64];
  const int tid = threadIdx.x;
  const int w = tid >> 6, lane = tid & 63;
  const int quad = lane >> 4, l15 = lane & 15;
  const int bh = blockIdx.x, b = bh >> 4, h = bh & 15;
  // dispatch-round-aware qt map: per y-octave per CU; iteration sums uniform.
  const int y = blockIdx.y;
  const int qt = (y < 8) ? 31 - y : (y < 16) ? y - 8 : (y < 24) ? 39 - y : y - 16;
  const unsigned short* base = qkv + (size_t)b * TSEQ * 3072 + h * 64;
  const int t = tid >> 2, dc = (tid & 3) * 16;   // K/Q staging: row t, 16 d's
  const int d0 = tid & 31, tg8 = tid >> 5;       // V staging: 2 d-rows, 8 t's

  // tile-0 K/V loads issued first (latency hides under Q staging)
  uint4 kreg0, kreg1;
  unsigned int vreg[8];
  {
    const unsigned short* gk = base + 1024 + (size_t)t * 3072 + dc;
    kreg0 = *(const uint4*)gk;
    kreg1 = *(const uint4*)(gk + 8);
    const unsigned short* gv = base + 2048 + (size_t)(tg8 * 8) * 3072 + 2 * d0;
#pragma unroll
    for (int s = 0; s < 8; s++)
      vreg[s] = *(const unsigned int*)(gv + (size_t)s * 3072);
  }
  {  // stage Q tile into Kp[1] + row sums of squares (v_dot2_f32_f16)
    const unsigned short* g = base + (size_t)(qt * 64 + t) * 3072 + dc;
    uint4 v0 = *(const uint4*)g;
    uint4 v1 = *(const uint4*)(g + 8);
    *(uint4*)&Kp[1][t * 72 + dc] = v0;
    *(uint4*)&Kp[1][t * 72 + dc + 8] = v1;
    float s = dot2acc(v0.x, 0.f);
    s = dot2acc(v0.y, s); s = dot2acc(v0.z, s); s = dot2acc(v0.w, s);
    s = dot2acc(v1.x, s); s = dot2acc(v1.y, s); s = dot2acc(v1.z, s);
    s = dot2acc(v1.w, s);
    s += __shfl_xor(s, 1);
    s += __shfl_xor(s, 2);
    if ((tid & 3) == 0) qsq[t] = s;
  }
  // commit K [t][d] + ksq + V^T [d][t] from regs into buffer `buf`
  auto commit = [&](int buf) {
    *(uint4*)&Kp[buf][t * 72 + dc] = kreg0;
    *(uint4*)&Kp[buf][t * 72 + dc + 8] = kreg1;
    float s = dot2acc(kreg0.x, 0.f);
    s = dot2acc(kreg0.y, s); s = dot2acc(kreg0.z, s); s = dot2acc(kreg0.w, s);
    s = dot2acc(kreg1.x, s); s = dot2acc(kreg1.y, s); s = dot2acc(kreg1.z, s);
    s = dot2acc(kreg1.w, s);
    s += __shfl_xor(s, 1);
    s += __shfl_xor(s, 2);
    if ((tid & 3) == 0) ksq[buf][t] = s;
    // V^T repack: one v_perm_b32 per output dword (lo-halves / hi-halves)
    uint4 LO, HI;
    LO.x = __builtin_amdgcn_perm(vreg[1], vreg[0], 0x05040100u);
    HI.x = __builtin_amdgcn_perm(vreg[1], vreg[0], 0x07060302u);
    LO.y = __builtin_amdgcn_perm(vreg[3], vreg[2], 0x05040100u);
    HI.y = __builtin_amdgcn_perm(vreg[3], vreg[2], 0x07060302u);
    LO.z = __builtin_amdgcn_perm(vreg[5], vreg[4], 0x05040100u);
    HI.z = __builtin_amdgcn_perm(vreg[5], vreg[4], 0x07060302u);
    LO.w = __builtin_amdgcn_perm(vreg[7], vreg[6], 0x05040100u);
    HI.w = __builtin_amdgcn_perm(vreg[7], vreg[6], 0x07060302u);
    *(uint4*)&Vt[buf][(2 * d0) * 72 + tg8 * 8] = LO;
    *(uint4*)&Vt[buf][(2 * d0 + 1) * 72 + tg8 * 8] = HI;
  };
  commit(0);
  if (qt >= 1) {  // prefetch tile 1
    const unsigned short* gk = base + 1024 + (size_t)(64 + t) * 3072 + dc;
    kreg0 = *(const uint4*)gk;
    kreg1 = *(const uint4*)(gk + 8);
    const unsigned short* gv = base + 2048 + (size_t)(64 + tg8 * 8) * 3072 + 2 * d0;
#pragma unroll
    for (int s = 0; s < 8; s++)
      vreg[s] = *(const unsigned int*)(gv + (size_t)s * 3072);
  }
  __syncthreads();  // Q (Kp[1]) + tile0 (Kp[0]/Vt[0]/ksq[0]) visible
  // hoisted loop-invariant Q fragments (wave w, q rows 16w..16w+16)
  const f16x8 aq0 = *(const f16x8*)&Kp[1][(w * 16 + l15) * 72 + quad * 8];
  const f16x8 aq1 = *(const f16x8*)&Kp[1][(w * 16 + l15) * 72 + 32 + quad * 8];
  const f16x8 onesf = {(_Float16)1.f, (_Float16)1.f, (_Float16)1.f, (_Float16)1.f,
                       (_Float16)1.f, (_Float16)1.f, (_Float16)1.f, (_Float16)1.f};
  const int ql = w * 16 + l15;            // this lane's q row (tile-local)
  const float qsq_eps = qsq[ql] + 1e-6f;  // loop-invariant
  __syncthreads();  // all Q-frag reads done before iter0 commits into Kp[1]

  f32x4 accO[4] = {};                    // O^T: lane q = l15, d = 16i+quad*4+r
  float m_run = 0.f;                     // scores >= 0 so 0 is a valid init max
  float l_acc = 0.f;                     // l in O^T layout: lane q = l15

  for (int kt = 0; kt <= qt; kt++) {
    const int cur = kt & 1;
    // S^T = K Q^T : rows t (quad*4+r per nt), cols q (l15) — critical path first
    f32x4 accS[4] = {};
#pragma unroll
    for (int nt = 0; nt < 4; nt++) {
      const f16x8 bk0 = *(const f16x8*)&Kp[cur][(nt * 16 + l15) * 72 + quad * 8];
      const f16x8 bk1 = *(const f16x8*)&Kp[cur][(nt * 16 + l15) * 72 + 32 + quad * 8];
      accS[nt] = MFMA16(bk0, aq0, accS[nt]);
      accS[nt] = MFMA16(bk1, aq1, accS[nt]);
    }
    // scores, packed-f32 vector form: lane q = ql, t = nt*16 + quad*4 + r
    f32x4 sc[4];
#pragma unroll
    for (int nt = 0; nt < 4; nt++) {
      const f32x4 k4 = *(const f32x4*)&ksq[cur][nt * 16 + quad * 4];
      const f32x4 dv = accS[nt];
      f32x4 den = (k4 + qsq_eps) + dv * -2.f;  // contracts to v_pk_fma_f32
      f32x4 rc;
      rc[0] = __builtin_amdgcn_rcpf(den[0]);
      rc[1] = __builtin_amdgcn_rcpf(den[1]);
      rc[2] = __builtin_amdgcn_rcpf(den[2]);
      rc[3] = __builtin_amdgcn_rcpf(den[3]);
      sc[nt] = dv * dv * rc;                   // v_pk_mul_f32 x2
    }
    if (kt == qt) {  // causal mask, uniform branch (last iteration only)
#pragma unroll
      for (int nt = 0; nt < 4; nt++)
#pragma unroll
        for (int r = 0; r < 4; r++)
          if (nt * 16 + quad * 4 + r > ql) sc[nt][r] = -1e30f;
    }
    // row max: vector pk_max tree, then horizontal, then cross-quad
    const f32x4 t01 = __builtin_elementwise_max(sc[0], sc[1]);
    const f32x4 t23 = __builtin_elementwise_max(sc[2], sc[3]);
    const f32x4 t4 = __builtin_elementwise_max(t01, t23);
    float tm = fmaxf(fmaxf(t4[0], t4[1]), fmaxf(t4[2], t4[3]));
    tm = fmaxf(tm, __shfl_xor(tm, 16));
    tm = fmaxf(tm, __shfl_xor(tm, 32));
    const float mn = fmaxf(m_run, tm);
    const float alpha = __expf(m_run - mn);
    m_run = mn;
    // P = exp(s - m) packed to f16 pairs
    unsigned int pa[4], pb[4];
#pragma unroll
    for (int nt = 0; nt < 4; nt++) {
      const f32x4 e = sc[nt] - m_run;          // v_pk_add_f32 x2
      pa[nt] = pk_f16(__expf(e[0]), __expf(e[1]));
      pb[nt] = pk_f16(__expf(e[2]), __expf(e[3]));
    }
    // commit tile kt+1 into the other buffer (vmcnt wait lands here, ~1 iter
    // after load issue); then issue loads for tile kt+2.
    if (kt < qt) commit(cur ^ 1);
    if (kt + 2 <= qt) {
      const unsigned short* gk = base + 1024 + (size_t)((kt + 2) * 64 + t) * 3072 + dc;
      kreg0 = *(const uint4*)gk;
      kreg1 = *(const uint4*)(gk + 8);
      const unsigned short* gv =
          base + 2048 + (size_t)((kt + 2) * 64 + tg8 * 8) * 3072 + 2 * d0;
#pragma unroll
      for (int s = 0; s < 8; s++)
        vreg[s] = *(const unsigned int*)(gv + (size_t)s * 3072);
    }
    // redistribute P into PV B-frags: (w0,w2) = permlane16(permlane32(lo,hi))
    union { f16x8 v; unsigned int u[4]; } bp0, bp1;
    {
      u32x2 s0 = __builtin_amdgcn_permlane32_swap(pa[0], pa[1], false, false);
      u32x2 s1 = __builtin_amdgcn_permlane16_swap(s0.x, s0.y, false, false);
      bp0.u[0] = s1.x; bp0.u[2] = s1.y;
      s0 = __builtin_amdgcn_permlane32_swap(pb[0], pb[1], false, false);
      s1 = __builtin_amdgcn_permlane16_swap(s0.x, s0.y, false, false);
      bp0.u[1] = s1.x; bp0.u[3] = s1.y;
      s0 = __builtin_amdgcn_permlane32_swap(pa[2], pa[3], false, false);
      s1 = __builtin_amdgcn_permlane16_swap(s0.x, s0.y, false, false);
      bp1.u[0] = s1.x; bp1.u[2] = s1.y;
      s0 = __builtin_amdgcn_permlane32_swap(pb[2], pb[3], false, false);
      s1 = __builtin_amdgcn_permlane16_swap(s0.x, s0.y, false, false);
      bp1.u[1] = s1.x; bp1.u[3] = s1.y;
    }
    // rescale O^T (vector: v_pk_mul_f32 x2 each), l via ones-MFMA
#pragma unroll
    for (int i = 0; i < 4; i++) accO[i] *= alpha;
    f32x4 accL = {};  // D = ones * P^T -> col=l15=q, rows identical = sum_t P[q][t]
    accL = MFMA16(onesf, bp0.v, accL);
    accL = MFMA16(onesf, bp1.v, accL);
#pragma unroll
    for (int i = 0; i < 4; i++) {
      const f16x8 av0 = *(const f16x8*)&Vt[cur][(i * 16 + l15) * 72 + quad * 8];
      const f16x8 av1 = *(const f16x8*)&Vt[cur][(i * 16 + l15) * 72 + 32 + quad * 8];
      accO[i] = MFMA16(av0, bp0.v, accO[i]);
      accO[i] = MFMA16(av1, bp1.v, accO[i]);
    }
    l_acc = l_acc * alpha + accL[0];
    __syncthreads();  // single barrier: reads of cur done; writes of cur^1 done
  }

  // finalize: divide by l (already in O^T lane layout), transpose via Kp[0], store
  const float linv = 1.0f / l_acc;
#pragma unroll
  for (int i = 0; i < 4; i++)
#pragma unroll
    for (int r = 0; r < 4; r++)
      Kp[0][(w * 16 + l15) * 72 + i * 16 + quad * 4 + r] = f2h(accO[i][r] * linv);
  __syncthreads();
  {
    uint4 o0 = *(const uint4*)&Kp[0][t * 72 + dc];
    uint4 o1 = *(const uint4*)&Kp[0][t * 72 + dc + 8];
    unsigned short* g = outp + (size_t)(b * TSEQ + qt * 64 + t) * 1024 + h * 64 + dc;
    *(uint4*)g = o0;
    *(uint4*)(g + 8) = o1;
  }
}

extern "C" void kernel_launch(void* const* d_in, const int* in_sizes, int n_in,
                              void* d_out, int out_size, void* d_ws, size_t ws_size,
                              hipStream_t stream) {
  (void)in_sizes; (void)n_in; (void)out_size; (void)ws_size;
  const float* x     = (const float*)d_in[0];  // [2,2048,1024] fp32
  const float* w_qkv = (const float*)d_in[1];  // [1024,3072]   fp32
  const float* b_qkv = (const float*)d_in[2];  // [3072]        fp32
  const float* w_out = (const float*)d_in[3];  // [1024,1024]   fp32
  const float* b_out = (const float*)d_in[4];  // [1024]        fp32
  float* out = (float*)d_out;                  // [2,2048,1024] fp32

  unsigned short* wqkvT  = (unsigned short*)d_ws;                    // [3072][1024] fp16
  unsigned short* woT    = wqkvT + (size_t)3072 * 1024;              // [1024][1024] fp16
  unsigned short* qkvws  = woT + (size_t)1024 * 1024;                // [4096][3072] fp16
  unsigned short* xh     = qkvws + (size_t)4096 * 3072;              // [4096][1024] fp16
  unsigned short* attnws = xh;  // alias: xh dead after gemm1, attnws born at yat_attn

  prep<<<dim3(6144), 256, 0, stream>>>(x, xh, w_qkv, wqkvT, w_out, woT);
  // gemm1: 24x32 tiles = 768 wgs (%8==0); gemm2: 16x32 = 512 wgs (%8==0)
  gemm_bt<128, false, 24><<<dim3(768), 256, 0, stream>>>(xh, wqkvT, b_qkv, qkvws, 3072, 1024, 768);
  yat_attn<<<dim3(BATCH * 16, 32), 256, 0, stream>>>(qkvws, attnws);
  gemm_bt<64, true, 16><<<dim3(512), 256, 0, stream>>>(attnws, woT, b_out, out, 1024, 1024, 512);
}